// Round 4
// baseline (383.171 us; speedup 1.0000x reference)
//
#include <hip/hip_runtime.h>
#include <math.h>

#define NN 4096
#define MM 64
#define K1_THREADS 256
#define K1_CHUNKS 8               // blocks per batch in phase A
#define ROWS_PER_CHUNK (NN / K1_CHUNKS)   // 512
#define K2_THREADS 1024

// DPP row_shr accumulate: lane i += lane (i-N) within its 16-lane row.
// After N=1,2,4,8, lane 15 of each 16-lane segment holds the full segment sum.
template <int CTRL>
__device__ __forceinline__ float dpp_add(float v) {
    int r = __builtin_amdgcn_update_dpp(0, __float_as_int(v), CTRL, 0xf, 0xf, true);
    return v + __int_as_float(r);
}

__device__ __forceinline__ float wave_red_sum(float v) {
#pragma unroll
    for (int o = 32; o > 0; o >>= 1) v += __shfl_down(v, o, 64);
    return v;
}
__device__ __forceinline__ float wave_red_max(float v) {
#pragma unroll
    for (int o = 32; o > 0; o >>= 1) v = fmaxf(v, __shfl_down(v, o, 64));
    return v;
}

// Block-wide reductions over 1024 threads (16 waves). scratch needs >= 17 floats.
__device__ __forceinline__ float block_sum(float v, float* scratch) {
    const int tid = threadIdx.x;
    const int lane = tid & 63, wid = tid >> 6;
    v = wave_red_sum(v);
    if (lane == 0) scratch[wid] = v;
    __syncthreads();
    if (tid < 64) {
        float x = (tid < 16) ? scratch[tid] : 0.0f;
        x = wave_red_sum(x);
        if (tid == 0) scratch[16] = x;
    }
    __syncthreads();
    float r = scratch[16];
    __syncthreads();
    return r;
}
__device__ __forceinline__ float block_max(float v, float* scratch) {
    const int tid = threadIdx.x;
    const int lane = tid & 63, wid = tid >> 6;
    v = wave_red_max(v);
    if (lane == 0) scratch[wid] = v;
    __syncthreads();
    if (tid < 64) {
        float x = (tid < 16) ? scratch[tid] : -INFINITY;
        x = wave_red_max(x);
        if (tid == 0) scratch[16] = x;
    }
    __syncthreads();
    float r = scratch[16];
    __syncthreads();
    return r;
}

// ---- Kernel 1: stream memory, emit per-row {dot, sumsq} to workspace ----
// grid = B * K1_CHUNKS blocks of 256 threads. Each block covers 512 rows.
// Per iter the block reads 4 KB contiguous (16 rows); 16-lane DPP segments.
extern "C" __global__ void __launch_bounds__(K1_THREADS)
ntm_phase_a(const float* __restrict__ memory, const float* __restrict__ k,
            float2* __restrict__ ws2) {
    const int tid = threadIdx.x;
    const int b = blockIdx.x >> 3;
    const int c = blockIdx.x & (K1_CHUNKS - 1);
    const float* __restrict__ base =
        memory + (size_t)b * NN * MM + (size_t)c * ROWS_PER_CHUNK * MM;

    const int m4 = (tid & 15) * 4;
    const float4 kf = *(const float4*)(k + b * MM + m4);

    // rotate start offset per block to decorrelate the HBM streams
    const int phase = (blockIdx.x * 5) & 31;

#pragma unroll 4
    for (int t = 0; t < 32; ++t) {
        const int it = (t + phase) & 31;
        const float4 mv = *(const float4*)(base + (size_t)it * 1024 + tid * 4);
        float d = mv.x * kf.x + mv.y * kf.y + mv.z * kf.z + mv.w * kf.w;
        float q = mv.x * mv.x + mv.y * mv.y + mv.z * mv.z + mv.w * mv.w;
        d = dpp_add<0x111>(d);
        d = dpp_add<0x112>(d);
        d = dpp_add<0x114>(d);
        d = dpp_add<0x118>(d);
        q = dpp_add<0x111>(q);
        q = dpp_add<0x112>(q);
        q = dpp_add<0x114>(q);
        q = dpp_add<0x118>(q);
        if ((tid & 15) == 15) {
            const int n = c * ROWS_PER_CHUNK + it * 16 + (tid >> 4);
            ws2[(size_t)b * NN + n] = make_float2(d, q);
        }
    }
}

// ---- Kernel 2: softmax + gate + circular shift + sharpen + normalize ----
extern "C" __global__ void __launch_bounds__(K2_THREADS)
ntm_phase_b(const float2* __restrict__ ws2, const float* __restrict__ k,
            const float* __restrict__ beta, const float* __restrict__ prev_w,
            const float* __restrict__ g, const float* __restrict__ s,
            const float* __restrict__ gamma, float* __restrict__ out) {
    __shared__ float wg[NN];     // 16 KB
    __shared__ float scratch[32];
    __shared__ float knorm_sh;

    const int b = blockIdx.x;
    const int tid = threadIdx.x;

    // prev_w early (coalesced), scalars
    float pw[4];
#pragma unroll
    for (int j = 0; j < 4; ++j)
        pw[j] = prev_w[(size_t)b * NN + tid + j * K2_THREADS];
    const float beta_b = beta[b];
    const float g_b = g[b];
    const float s0 = s[b * 3], s1 = s[b * 3 + 1], s2 = s[b * 3 + 2];
    const float gamma_b = gamma[b];

    if (tid < 64) {
        const float kv = k[b * MM + tid];
        const float sk = wave_red_sum(kv * kv);
        if (tid == 0) knorm_sh = fmaxf(sqrtf(sk), 1e-8f);
    }
    __syncthreads();
    const float knorm = knorm_sh;

    // ---- similarity + block max ----
    float val[4];
    float lmax = -INFINITY;
#pragma unroll
    for (int j = 0; j < 4; ++j) {
        const int n = tid + j * K2_THREADS;
        const float2 dq = ws2[(size_t)b * NN + n];
        const float mn = fmaxf(sqrtf(dq.y), 1e-8f);
        const float v = beta_b * (dq.x / (knorm * mn));
        val[j] = v;
        lmax = fmaxf(lmax, v);
    }
    const float mx = block_max(lmax, scratch);

    // ---- softmax ----
    float e[4];
    float lsum = 0.0f;
#pragma unroll
    for (int j = 0; j < 4; ++j) {
        e[j] = expf(val[j] - mx);
        lsum += e[j];
    }
    const float sumE = block_sum(lsum, scratch);

    // ---- gated interpolation into LDS ----
#pragma unroll
    for (int j = 0; j < 4; ++j) {
        const int n = tid + j * K2_THREADS;
        const float wc = e[j] / sumE;
        wg[n] = g_b * wc + (1.0f - g_b) * pw[j];
    }
    __syncthreads();

    // ---- circular 3-tap shift, sharpen, normalize ----
    float wp[4];
    float lsum2 = 0.0f;
#pragma unroll
    for (int j = 0; j < 4; ++j) {
        const int n = tid + j * K2_THREADS;
        const int nm = (n + NN - 1) & (NN - 1);
        const int np_ = (n + 1) & (NN - 1);
        const float ws = s0 * wg[nm] + s1 * wg[n] + s2 * wg[np_];
        const float p = (float)pow((double)ws, (double)gamma_b);
        wp[j] = p;
        lsum2 += p;
    }
    const float sumP = block_sum(lsum2, scratch);
    const float denom = sumP + 1e-16f;
#pragma unroll
    for (int j = 0; j < 4; ++j) {
        const int n = tid + j * K2_THREADS;
        out[(size_t)b * NN + n] = wp[j] / denom;
    }
}

extern "C" void kernel_launch(void* const* d_in, const int* in_sizes, int n_in,
                              void* d_out, int out_size, void* d_ws, size_t ws_size,
                              hipStream_t stream) {
    const float* memory = (const float*)d_in[0];
    const float* k      = (const float*)d_in[1];
    const float* beta   = (const float*)d_in[2];
    const float* prev_w = (const float*)d_in[3];
    const float* g      = (const float*)d_in[4];
    const float* s      = (const float*)d_in[5];
    const float* gamma  = (const float*)d_in[6];
    float* out = (float*)d_out;
    float2* ws2 = (float2*)d_ws;

    const int B = in_sizes[2];  // beta is [B,1]
    ntm_phase_a<<<B * K1_CHUNKS, K1_THREADS, 0, stream>>>(memory, k, ws2);
    ntm_phase_b<<<B, K2_THREADS, 0, stream>>>(ws2, k, beta, prev_w, g, s, gamma, out);
}

// Round 5
// 375.557 us; speedup vs baseline: 1.0203x; 1.0203x over previous
//
#include <hip/hip_runtime.h>
#include <math.h>

#define NN 4096
#define MM 64
#define A_BLOCKS 2048
#define A_THREADS 256
#define A_T (A_BLOCKS * A_THREADS)          // 524288 threads
#define A_ITERS ((256 * NN * MM / 4) / A_T) // 16M float4 / 524288 = 32
#define K2_THREADS 1024

// DPP row_shr accumulate: lane i += lane (i-N) within its 16-lane row.
// After N=1,2,4,8, lane 15 of each 16-lane segment holds the full segment sum.
template <int CTRL>
__device__ __forceinline__ float dpp_add(float v) {
    int r = __builtin_amdgcn_update_dpp(0, __float_as_int(v), CTRL, 0xf, 0xf, true);
    return v + __int_as_float(r);
}

__device__ __forceinline__ float wave_red_sum(float v) {
#pragma unroll
    for (int o = 32; o > 0; o >>= 1) v += __shfl_down(v, o, 64);
    return v;
}
__device__ __forceinline__ float wave_red_max(float v) {
#pragma unroll
    for (int o = 32; o > 0; o >>= 1) v = fmaxf(v, __shfl_down(v, o, 64));
    return v;
}

// Block-wide reductions over 1024 threads (16 waves). scratch needs >= 17 floats.
__device__ __forceinline__ float block_sum(float v, float* scratch) {
    const int tid = threadIdx.x;
    const int lane = tid & 63, wid = tid >> 6;
    v = wave_red_sum(v);
    if (lane == 0) scratch[wid] = v;
    __syncthreads();
    if (tid < 64) {
        float x = (tid < 16) ? scratch[tid] : 0.0f;
        x = wave_red_sum(x);
        if (tid == 0) scratch[16] = x;
    }
    __syncthreads();
    float r = scratch[16];
    __syncthreads();
    return r;
}
__device__ __forceinline__ float block_max(float v, float* scratch) {
    const int tid = threadIdx.x;
    const int lane = tid & 63, wid = tid >> 6;
    v = wave_red_max(v);
    if (lane == 0) scratch[wid] = v;
    __syncthreads();
    if (tid < 64) {
        float x = (tid < 16) ? scratch[tid] : -INFINITY;
        x = wave_red_max(x);
        if (tid == 0) scratch[16] = x;
    }
    __syncthreads();
    float r = scratch[16];
    __syncthreads();
    return r;
}

// ---- Kernel 1: lockstep grid-stride stream of memory ----
// Global thread i reads float4 #(i + t*T): at any instant the whole GPU
// touches one dense 8 MB window, exactly like the 6.3 TB/s copy ubench.
// Each 16-lane segment covers one M=64 row; DPP-reduce; lane 15 scatters
// {dot, sumsq} to ws2[global_row].
extern "C" __global__ void __launch_bounds__(A_THREADS)
ntm_phase_a(const float* __restrict__ memory, const float* __restrict__ k,
            float2* __restrict__ ws2) {
    const int tid = blockIdx.x * A_THREADS + threadIdx.x;
    const float4* __restrict__ mem4 = (const float4*)memory;
    const int lane16 = tid & 15;          // position of this float4 within its row

#pragma unroll 4
    for (int t = 0; t < A_ITERS; ++t) {
        const size_t idx = (size_t)tid + (size_t)t * A_T;
        const float4 mv = mem4[idx];
        const int gr = (int)(idx >> 4);   // global row in [0, B*NN)
        const int b = gr >> 12;           // NN = 4096 rows per batch
        const float4 kf = *(const float4*)(k + b * MM + lane16 * 4);
        float d = mv.x * kf.x + mv.y * kf.y + mv.z * kf.z + mv.w * kf.w;
        float q = mv.x * mv.x + mv.y * mv.y + mv.z * mv.z + mv.w * mv.w;
        d = dpp_add<0x111>(d);
        d = dpp_add<0x112>(d);
        d = dpp_add<0x114>(d);
        d = dpp_add<0x118>(d);
        q = dpp_add<0x111>(q);
        q = dpp_add<0x112>(q);
        q = dpp_add<0x114>(q);
        q = dpp_add<0x118>(q);
        if (lane16 == 15) ws2[gr] = make_float2(d, q);
    }
}

// ---- Kernel 2: softmax + gate + circular shift + sharpen + normalize ----
extern "C" __global__ void __launch_bounds__(K2_THREADS)
ntm_phase_b(const float2* __restrict__ ws2, const float* __restrict__ k,
            const float* __restrict__ beta, const float* __restrict__ prev_w,
            const float* __restrict__ g, const float* __restrict__ s,
            const float* __restrict__ gamma, float* __restrict__ out) {
    __shared__ float wg[NN];     // 16 KB
    __shared__ float scratch[32];
    __shared__ float knorm_sh;

    const int b = blockIdx.x;
    const int tid = threadIdx.x;

    // prev_w early (coalesced), scalars
    float pw[4];
#pragma unroll
    for (int j = 0; j < 4; ++j)
        pw[j] = prev_w[(size_t)b * NN + tid + j * K2_THREADS];
    const float beta_b = beta[b];
    const float g_b = g[b];
    const float s0 = s[b * 3], s1 = s[b * 3 + 1], s2 = s[b * 3 + 2];
    const float gamma_b = gamma[b];

    if (tid < 64) {
        const float kv = k[b * MM + tid];
        const float sk = wave_red_sum(kv * kv);
        if (tid == 0) knorm_sh = fmaxf(sqrtf(sk), 1e-8f);
    }
    __syncthreads();
    const float knorm = knorm_sh;

    // ---- similarity + block max ----
    float val[4];
    float lmax = -INFINITY;
#pragma unroll
    for (int j = 0; j < 4; ++j) {
        const int n = tid + j * K2_THREADS;
        const float2 dq = ws2[(size_t)b * NN + n];
        const float mn = fmaxf(sqrtf(dq.y), 1e-8f);
        const float v = beta_b * (dq.x / (knorm * mn));
        val[j] = v;
        lmax = fmaxf(lmax, v);
    }
    const float mx = block_max(lmax, scratch);

    // ---- softmax ----
    float e[4];
    float lsum = 0.0f;
#pragma unroll
    for (int j = 0; j < 4; ++j) {
        e[j] = expf(val[j] - mx);
        lsum += e[j];
    }
    const float sumE = block_sum(lsum, scratch);

    // ---- gated interpolation into LDS ----
#pragma unroll
    for (int j = 0; j < 4; ++j) {
        const int n = tid + j * K2_THREADS;
        const float wc = e[j] / sumE;
        wg[n] = g_b * wc + (1.0f - g_b) * pw[j];
    }
    __syncthreads();

    // ---- circular 3-tap shift, sharpen, normalize ----
    float wp[4];
    float lsum2 = 0.0f;
#pragma unroll
    for (int j = 0; j < 4; ++j) {
        const int n = tid + j * K2_THREADS;
        const int nm = (n + NN - 1) & (NN - 1);
        const int np_ = (n + 1) & (NN - 1);
        const float ws = s0 * wg[nm] + s1 * wg[n] + s2 * wg[np_];
        const float p = (float)pow((double)ws, (double)gamma_b);
        wp[j] = p;
        lsum2 += p;
    }
    const float sumP = block_sum(lsum2, scratch);
    const float denom = sumP + 1e-16f;
#pragma unroll
    for (int j = 0; j < 4; ++j) {
        const int n = tid + j * K2_THREADS;
        out[(size_t)b * NN + n] = wp[j] / denom;
    }
}

extern "C" void kernel_launch(void* const* d_in, const int* in_sizes, int n_in,
                              void* d_out, int out_size, void* d_ws, size_t ws_size,
                              hipStream_t stream) {
    const float* memory = (const float*)d_in[0];
    const float* k      = (const float*)d_in[1];
    const float* beta   = (const float*)d_in[2];
    const float* prev_w = (const float*)d_in[3];
    const float* g      = (const float*)d_in[4];
    const float* s      = (const float*)d_in[5];
    const float* gamma  = (const float*)d_in[6];
    float* out = (float*)d_out;
    float2* ws2 = (float2*)d_ws;

    const int B = in_sizes[2];  // beta is [B,1]
    ntm_phase_a<<<A_BLOCKS, A_THREADS, 0, stream>>>(memory, k, ws2);
    ntm_phase_b<<<B, K2_THREADS, 0, stream>>>(ws2, k, beta, prev_w, g, s, gamma, out);
}